// Round 3
// baseline (521.242 us; speedup 1.0000x reference)
//
#include <hip/hip_runtime.h>
#include <cstdint>

typedef __attribute__((ext_vector_type(8))) __bf16 bf16x8;
typedef __attribute__((ext_vector_type(4))) float f32x4;

__device__ __forceinline__ unsigned short f2bf(float f) {
  union { float f; unsigned int u; } v; v.f = f;
  unsigned int u = v.u;
  return (unsigned short)((u + 0x7FFFu + ((u >> 16) & 1u)) >> 16);
}

__device__ __forceinline__ void load_lds16(const unsigned short* g, unsigned short* l) {
  __builtin_amdgcn_global_load_lds(
      (const __attribute__((address_space(1))) unsigned int*)g,
      (__attribute__((address_space(3))) unsigned int*)l, 16, 0, 0);
}

// ---------------- all weight transposes fused: fp32 [K][N] -> bf16 [N][K] ----------------
__global__ void transpose_all(const float* __restrict__ wq, const float* __restrict__ wk,
                              const float* __restrict__ wv, const float* __restrict__ w_proj,
                              const float* __restrict__ w1, const float* __restrict__ w2,
                              unsigned short* __restrict__ qkvt, unsigned short* __restrict__ projt,
                              unsigned short* __restrict__ w1t, unsigned short* __restrict__ w2t) {
  __shared__ float tile[32][33];
  const int id = blockIdx.x;
  const float* src;
  unsigned short* dst;
  int K, N, nt, kt;
  if (id < 3072) {  // qkv: which(3) x slice(16) x ntile(2) x ktile(32)
    const int which = id >> 10, rem = id & 1023;
    const int slice = rem >> 6, t = rem & 63;
    src = (which == 0 ? wq : which == 1 ? wk : wv) + (long)slice * 65536;
    dst = qkvt + (long)which * 1048576 + (long)slice * 65536;
    K = 1024; N = 64;
    nt = (t & 1) * 32; kt = (t >> 1) * 32;
  } else if (id < 4096) {  // proj: 32x32 tiles
    const int t = id - 3072;
    src = w_proj; dst = projt; K = 1024; N = 1024;
    nt = (t & 31) * 32; kt = (t >> 5) * 32;
  } else if (id < 8192) {  // w1: ntile 128 x ktile 32
    const int t = id - 4096;
    src = w1; dst = w1t; K = 1024; N = 4096;
    nt = (t & 127) * 32; kt = (t >> 7) * 32;
  } else {  // w2: ntile 32 x ktile 128
    const int t = id - 8192;
    src = w2; dst = w2t; K = 4096; N = 1024;
    nt = (t & 31) * 32; kt = (t >> 5) * 32;
  }
  const int tx = threadIdx.x & 31, ty = threadIdx.x >> 5;
#pragma unroll
  for (int i = 0; i < 4; i++)
    tile[ty + 8 * i][tx] = src[(long)(kt + ty + 8 * i) * N + nt + tx];
  __syncthreads();
#pragma unroll
  for (int i = 0; i < 4; i++)
    dst[(long)(nt + ty + 8 * i) * K + kt + tx] = f2bf(tile[tx][ty + 8 * i]);
}

// ---------------- LayerNorm fp32 -> bf16 (one row of 1024 per block) ----------------
__global__ __launch_bounds__(256, 4) void ln_kernel(const float* __restrict__ x,
                                                    const float* __restrict__ g,
                                                    const float* __restrict__ b,
                                                    unsigned short* __restrict__ out) {
  const int row = blockIdx.x, tid = threadIdx.x;
  const int wave = tid >> 6, lane = tid & 63;
  const float4 xv = *(const float4*)&x[(long)row * 1024 + tid * 4];
  float s1 = xv.x + xv.y + xv.z + xv.w;
  float s2 = xv.x * xv.x + xv.y * xv.y + xv.z * xv.z + xv.w * xv.w;
#pragma unroll
  for (int m = 1; m < 64; m <<= 1) { s1 += __shfl_xor(s1, m); s2 += __shfl_xor(s2, m); }
  __shared__ float a1[4], a2[4];
  if (lane == 0) { a1[wave] = s1; a2[wave] = s2; }
  __syncthreads();
  s1 = a1[0] + a1[1] + a1[2] + a1[3];
  s2 = a2[0] + a2[1] + a2[2] + a2[3];
  const float mu = s1 * (1.f / 1024.f);
  const float var = s2 * (1.f / 1024.f) - mu * mu;
  const float rs = rsqrtf(var + 1e-5f);
  const float4 gv = *(const float4*)&g[tid * 4];
  const float4 bv = *(const float4*)&b[tid * 4];
  ushort4 o;
  o.x = f2bf((xv.x - mu) * rs * gv.x + bv.x);
  o.y = f2bf((xv.y - mu) * rs * gv.y + bv.y);
  o.z = f2bf((xv.z - mu) * rs * gv.z + bv.z);
  o.w = f2bf((xv.w - mu) * rs * gv.w + bv.w);
  *(ushort4*)&out[(long)row * 1024 + tid * 4] = o;
}

// ---------------- bf16 GEMM: C[M,N] = A[M,K] * Bt[N,K]^T, templated epilogue ----------------
#define EPI_QKV 0
#define EPI_F32 1
#define EPI_RELU 2

template <int EPI>
__global__ __launch_bounds__(256, 3) void gemm_bt(
    const unsigned short* __restrict__ A, const unsigned short* __restrict__ Bt,
    int M, int N, int K,
    const float* __restrict__ bias, const float* __restrict__ resid,
    float* __restrict__ outF, unsigned short* __restrict__ outB,
    unsigned short* __restrict__ qb, unsigned short* __restrict__ kb,
    unsigned short* __restrict__ vTb) {
  // LDS holds 16B chunks; chunk (m, kc) stored at physical pc = kc ^ (m&7) -> conflict-free b128 reads
  __shared__ __attribute__((aligned(16))) unsigned short Alds[128 * 64];
  __shared__ __attribute__((aligned(16))) unsigned short Blds[128 * 64];
  const int tid = threadIdx.x;
  const int wave = tid >> 6, lane = tid & 63;
  const int quad = lane >> 4, l15 = lane & 15;
  const long tM = (long)blockIdx.x * 128;
  const long tN = (long)blockIdx.y * 128;
  const int wm = (wave >> 1) * 64, wn = (wave & 1) * 64;

  const unsigned short* aP[4];
  const unsigned short* bP[4];
  unsigned short* lA[4];
  unsigned short* lB[4];
#pragma unroll
  for (int qq = 0; qq < 4; qq++) {
    int p = (qq * 4 + wave) * 64 + lane;
    int m = p >> 3;
    int kc = (p & 7) ^ (m & 7);
    aP[qq] = A + (tM + m) * K + kc * 8;
    bP[qq] = Bt + (tN + m) * K + kc * 8;
    lA[qq] = Alds + (qq * 4 + wave) * 512;  // wave-uniform base, lane*16B appended by HW
    lB[qq] = Blds + (qq * 4 + wave) * 512;
  }

  f32x4 acc[4][4];
#pragma unroll
  for (int i = 0; i < 4; i++)
#pragma unroll
    for (int j = 0; j < 4; j++) acc[i][j] = (f32x4){0.f, 0.f, 0.f, 0.f};

  for (int k0 = 0; k0 < K; k0 += 64) {
    __syncthreads();
#pragma unroll
    for (int qq = 0; qq < 4; qq++) {
      load_lds16(aP[qq], lA[qq]);
      load_lds16(bP[qq], lB[qq]);
      aP[qq] += 64;
      bP[qq] += 64;
    }
    __syncthreads();
#pragma unroll
    for (int ks = 0; ks < 2; ks++) {
      bf16x8 af[4], bfr[4];
#pragma unroll
      for (int mt = 0; mt < 4; mt++) {
        int ml = wm + mt * 16 + l15;
        int pc = (ks * 4 + quad) ^ (ml & 7);
        af[mt] = *(const bf16x8*)&Alds[(ml * 8 + pc) * 8];
      }
#pragma unroll
      for (int nt = 0; nt < 4; nt++) {
        int nl = wn + nt * 16 + l15;
        int pc = (ks * 4 + quad) ^ (nl & 7);
        bfr[nt] = *(const bf16x8*)&Blds[(nl * 8 + pc) * 8];
      }
#pragma unroll
      for (int mt = 0; mt < 4; mt++)
#pragma unroll
        for (int nt = 0; nt < 4; nt++)
          acc[mt][nt] = __builtin_amdgcn_mfma_f32_16x16x32_bf16(af[mt], bfr[nt], acc[mt][nt], 0, 0, 0);
    }
  }

#pragma unroll
  for (int mt = 0; mt < 4; mt++) {
#pragma unroll
    for (int nt = 0; nt < 4; nt++) {
      const long col = tN + wn + nt * 16 + l15;
      const long row0 = tM + wm + mt * 16 + quad * 4;
      if (EPI == EPI_F32) {
        const float bv = bias[col];
#pragma unroll
        for (int r = 0; r < 4; r++) {
          long idx = (row0 + r) * N + col;
          outF[idx] = acc[mt][nt][r] + bv + resid[idx];
        }
      } else if (EPI == EPI_RELU) {
        const float bv = bias[col];
#pragma unroll
        for (int r = 0; r < 4; r++) {
          float v = acc[mt][nt][r] + bv;
          outB[(row0 + r) * N + col] = f2bf(v > 0.f ? v : 0.f);
        }
      } else {  // EPI_QKV: scatter into q[bh][t][d], k[bh][t][d], vT[bh][d][t]
        const int which = (int)(col >> 10);
        const int hh = (int)((col >> 6) & 15);
        const int dd = (int)(col & 63);
        const int b = (int)(row0 >> 10), t0 = (int)(row0 & 1023);
        if (which == 2) {
          // rows r=0..3 are consecutive t -> pack one ushort4 store
          ushort4 pk;
          pk.x = f2bf(acc[mt][nt][0]);
          pk.y = f2bf(acc[mt][nt][1]);
          pk.z = f2bf(acc[mt][nt][2]);
          pk.w = f2bf(acc[mt][nt][3]);
          *(ushort4*)&vTb[(long)(b * 16 + hh) * 65536 + dd * 1024 + t0] = pk;
        } else {
          unsigned short* dst = (which == 0 ? qb : kb);
#pragma unroll
          for (int r = 0; r < 4; r++)
            dst[((b * 16 + hh) * 1024 + t0 + r) * 64 + dd] = f2bf(acc[mt][nt][r]);
        }
      }
    }
  }
}

// ---------------- flash attention (no-max softmax), barrier-free ----------------
// One (b*h, 64-row q-tile) per block; each wave owns 16 q-rows, fully independent.
// K/V fragments loaded straight from global (8KB tiles, L1-resident for the 4-wave reuse).
__global__ __launch_bounds__(256, 4) void attn_kernel(const unsigned short* __restrict__ qb,
                                                      const unsigned short* __restrict__ kb,
                                                      const unsigned short* __restrict__ vTb,
                                                      unsigned short* __restrict__ out) {
  __shared__ __attribute__((aligned(16))) unsigned short Plds[4 * 16 * 68];  // per-wave P transform
  const int bh = blockIdx.x;  // 0..127
  const int qt = blockIdx.y;  // 0..15
  const int tid = threadIdx.x;
  const int wave = tid >> 6, lane = tid & 63;
  const int quad = lane >> 4, l15 = lane & 15;

  const unsigned short* qp = qb + (long)bh * 65536;
  const unsigned short* kp = kb + (long)bh * 65536;
  const unsigned short* vp = vTb + (long)bh * 65536;

  const int qrow = qt * 64 + wave * 16 + l15;
  const bf16x8 qf0 = *(const bf16x8*)&qp[qrow * 64 + quad * 8];
  const bf16x8 qf1 = *(const bf16x8*)&qp[qrow * 64 + 32 + quad * 8];

  f32x4 O[4];
  float l_r[4] = {0.f, 0.f, 0.f, 0.f};
#pragma unroll
  for (int nt = 0; nt < 4; nt++) O[nt] = (f32x4){0.f, 0.f, 0.f, 0.f};

  unsigned short* Pl = Plds + wave * (16 * 68);
  const float cscale = 0.045084220f;  // (1/32) * log2(e)
  const int tloc = wave * 16 + quad * 4;

  for (int kt = 0; kt <= qt; kt++) {
    // S = Q K^T  (C-layout: col = s = nt*16+l15, row = quad*4+r)
    f32x4 S[4];
#pragma unroll
    for (int nt = 0; nt < 4; nt++) {
      const unsigned short* kr = kp + (kt * 64 + nt * 16 + l15) * 64;
      bf16x8 kf0 = *(const bf16x8*)&kr[quad * 8];
      bf16x8 kf1 = *(const bf16x8*)&kr[32 + quad * 8];
      f32x4 s = (f32x4){0.f, 0.f, 0.f, 0.f};
      s = __builtin_amdgcn_mfma_f32_16x16x32_bf16(qf0, kf0, s, 0, 0, 0);
      s = __builtin_amdgcn_mfma_f32_16x16x32_bf16(qf1, kf1, s, 0, 0, 0);
      S[nt] = s;
    }

    const bool diag = (kt == qt);
#pragma unroll
    for (int nt = 0; nt < 4; nt++) {
      const int sg = nt * 16 + l15;
#pragma unroll
      for (int r = 0; r < 4; r++) {
        float pv = exp2f(S[nt][r] * cscale);
        if (diag && sg > tloc + r) pv = 0.f;
        l_r[r] += pv;
        Pl[(quad * 4 + r) * 68 + sg] = f2bf(pv);
      }
    }
    __threadfence_block();  // drain ds_writes before cross-lane ds_reads

#pragma unroll
    for (int ks2 = 0; ks2 < 2; ks2++) {
      bf16x8 pa = *(const bf16x8*)&Pl[l15 * 68 + ks2 * 32 + quad * 8];
#pragma unroll
      for (int nt = 0; nt < 4; nt++) {
        bf16x8 vf = *(const bf16x8*)&vp[(nt * 16 + l15) * 1024 + kt * 64 + ks2 * 32 + quad * 8];
        O[nt] = __builtin_amdgcn_mfma_f32_16x16x32_bf16(pa, vf, O[nt], 0, 0, 0);
      }
    }
  }

  // final l reduction across the 16 lanes sharing each row
#pragma unroll
  for (int r = 0; r < 4; r++) {
    l_r[r] += __shfl_xor(l_r[r], 1);
    l_r[r] += __shfl_xor(l_r[r], 2);
    l_r[r] += __shfl_xor(l_r[r], 4);
    l_r[r] += __shfl_xor(l_r[r], 8);
    l_r[r] = __builtin_amdgcn_rcpf(l_r[r]);
  }

  const int b = bh >> 4, h = bh & 15;
#pragma unroll
  for (int nt = 0; nt < 4; nt++) {
#pragma unroll
    for (int r = 0; r < 4; r++) {
      const int t = qt * 64 + wave * 16 + quad * 4 + r;
      out[(long)(b * 1024 + t) * 1024 + h * 64 + nt * 16 + l15] = f2bf(O[nt][r] * l_r[r]);
    }
  }
}

extern "C" void kernel_launch(void* const* d_in, const int* in_sizes, int n_in,
                              void* d_out, int out_size, void* d_ws, size_t ws_size,
                              hipStream_t stream) {
  const float* x = (const float*)d_in[0];
  const float* wq = (const float*)d_in[1];
  const float* wk = (const float*)d_in[2];
  const float* wv = (const float*)d_in[3];
  const float* w_proj = (const float*)d_in[4];
  const float* b_proj = (const float*)d_in[5];
  const float* ln1_g = (const float*)d_in[6];
  const float* ln1_b = (const float*)d_in[7];
  const float* ln2_g = (const float*)d_in[8];
  const float* ln2_b = (const float*)d_in[9];
  const float* w1 = (const float*)d_in[10];
  const float* b1 = (const float*)d_in[11];
  const float* w2 = (const float*)d_in[12];
  const float* b2 = (const float*)d_in[13];
  float* out = (float*)d_out;

  char* w = (char*)d_ws;
  unsigned short* h1 = (unsigned short*)w;      w += (size_t)8192 * 1024 * 2;   // 16MB (reused as attnO)
  unsigned short* wqkvt = (unsigned short*)w;   w += (size_t)3072 * 1024 * 2;   // 6MB
  unsigned short* wprojt = (unsigned short*)w;  w += (size_t)1024 * 1024 * 2;   // 2MB
  unsigned short* w1t = (unsigned short*)w;     w += (size_t)4096 * 1024 * 2;   // 8MB
  unsigned short* w2t = (unsigned short*)w;     w += (size_t)4096 * 1024 * 2;   // 8MB
  unsigned short* qbuf = (unsigned short*)w;    w += (size_t)128 * 1024 * 64 * 2;  // 16MB (reused as h2)
  unsigned short* kbuf = (unsigned short*)w;    w += (size_t)128 * 1024 * 64 * 2;  // 16MB
  unsigned short* vTbuf = (unsigned short*)w;   w += (size_t)128 * 1024 * 64 * 2;  // 16MB
  unsigned short* act = (unsigned short*)w;     w += (size_t)8192 * 4096 * 2;      // 64MB
  unsigned short* attnO = h1;  // h1 dead after QKV gemm
  unsigned short* h2 = qbuf;   // qbuf dead after attention

  transpose_all<<<12288, 256, 0, stream>>>(wq, wk, wv, w_proj, w1, w2,
                                           wqkvt, wprojt, w1t, w2t);

  ln_kernel<<<8192, 256, 0, stream>>>(x, ln1_g, ln1_b, h1);

  gemm_bt<EPI_QKV><<<dim3(64, 24), 256, 0, stream>>>(h1, wqkvt, 8192, 3072, 1024,
                                                     nullptr, nullptr, nullptr, nullptr,
                                                     qbuf, kbuf, vTbuf);

  attn_kernel<<<dim3(128, 16), 256, 0, stream>>>(qbuf, kbuf, vTbuf, attnO);

  gemm_bt<EPI_F32><<<dim3(64, 8), 256, 0, stream>>>(attnO, wprojt, 8192, 1024, 1024,
                                                    b_proj, x, out, nullptr,
                                                    nullptr, nullptr, nullptr);

  ln_kernel<<<8192, 256, 0, stream>>>(out, ln2_g, ln2_b, h2);

  gemm_bt<EPI_RELU><<<dim3(64, 32), 256, 0, stream>>>(h2, w1t, 8192, 4096, 1024,
                                                      b1, nullptr, nullptr, act,
                                                      nullptr, nullptr, nullptr);

  gemm_bt<EPI_F32><<<dim3(64, 8), 256, 0, stream>>>(act, w2t, 8192, 1024, 4096,
                                                    b2, out, out, nullptr,
                                                    nullptr, nullptr, nullptr);
}

// Round 4
// 449.898 us; speedup vs baseline: 1.1586x; 1.1586x over previous
//
#include <hip/hip_runtime.h>
#include <cstdint>

typedef __attribute__((ext_vector_type(8))) __bf16 bf16x8;
typedef __attribute__((ext_vector_type(4))) float f32x4;

__device__ __forceinline__ unsigned short f2bf(float f) {
  union { float f; unsigned int u; } v; v.f = f;
  unsigned int u = v.u;
  return (unsigned short)((u + 0x7FFFu + ((u >> 16) & 1u)) >> 16);
}

__device__ __forceinline__ void load_lds16(const unsigned short* g, unsigned short* l) {
  __builtin_amdgcn_global_load_lds(
      (const __attribute__((address_space(1))) unsigned int*)g,
      (__attribute__((address_space(3))) unsigned int*)l, 16, 0, 0);
}

// ---------------- all weight transposes fused: fp32 [K][N] -> bf16 [N][K] ----------------
__global__ void transpose_all(const float* __restrict__ wq, const float* __restrict__ wk,
                              const float* __restrict__ wv, const float* __restrict__ w_proj,
                              const float* __restrict__ w1, const float* __restrict__ w2,
                              unsigned short* __restrict__ qkvt, unsigned short* __restrict__ projt,
                              unsigned short* __restrict__ w1t, unsigned short* __restrict__ w2t) {
  __shared__ float tile[32][33];
  const int id = blockIdx.x;
  const float* src;
  unsigned short* dst;
  int K, N, nt, kt;
  if (id < 3072) {  // qkv: which(3) x slice(16) x ntile(2) x ktile(32)
    const int which = id >> 10, rem = id & 1023;
    const int slice = rem >> 6, t = rem & 63;
    src = (which == 0 ? wq : which == 1 ? wk : wv) + (long)slice * 65536;
    dst = qkvt + (long)which * 1048576 + (long)slice * 65536;
    K = 1024; N = 64;
    nt = (t & 1) * 32; kt = (t >> 1) * 32;
  } else if (id < 4096) {  // proj: 32x32 tiles
    const int t = id - 3072;
    src = w_proj; dst = projt; K = 1024; N = 1024;
    nt = (t & 31) * 32; kt = (t >> 5) * 32;
  } else if (id < 8192) {  // w1: ntile 128 x ktile 32
    const int t = id - 4096;
    src = w1; dst = w1t; K = 1024; N = 4096;
    nt = (t & 127) * 32; kt = (t >> 7) * 32;
  } else {  // w2: ntile 32 x ktile 128
    const int t = id - 8192;
    src = w2; dst = w2t; K = 4096; N = 1024;
    nt = (t & 31) * 32; kt = (t >> 5) * 32;
  }
  const int tx = threadIdx.x & 31, ty = threadIdx.x >> 5;
#pragma unroll
  for (int i = 0; i < 4; i++)
    tile[ty + 8 * i][tx] = src[(long)(kt + ty + 8 * i) * N + nt + tx];
  __syncthreads();
#pragma unroll
  for (int i = 0; i < 4; i++)
    dst[(long)(nt + ty + 8 * i) * K + kt + tx] = f2bf(tile[tx][ty + 8 * i]);
}

// ---------------- LayerNorm fp32 -> bf16 (one row of 1024 per block) ----------------
__global__ __launch_bounds__(256, 4) void ln_kernel(const float* __restrict__ x,
                                                    const float* __restrict__ g,
                                                    const float* __restrict__ b,
                                                    unsigned short* __restrict__ out) {
  const int row = blockIdx.x, tid = threadIdx.x;
  const int wave = tid >> 6, lane = tid & 63;
  const float4 xv = *(const float4*)&x[(long)row * 1024 + tid * 4];
  float s1 = xv.x + xv.y + xv.z + xv.w;
  float s2 = xv.x * xv.x + xv.y * xv.y + xv.z * xv.z + xv.w * xv.w;
#pragma unroll
  for (int m = 1; m < 64; m <<= 1) { s1 += __shfl_xor(s1, m); s2 += __shfl_xor(s2, m); }
  __shared__ float a1[4], a2[4];
  if (lane == 0) { a1[wave] = s1; a2[wave] = s2; }
  __syncthreads();
  s1 = a1[0] + a1[1] + a1[2] + a1[3];
  s2 = a2[0] + a2[1] + a2[2] + a2[3];
  const float mu = s1 * (1.f / 1024.f);
  const float var = s2 * (1.f / 1024.f) - mu * mu;
  const float rs = rsqrtf(var + 1e-5f);
  const float4 gv = *(const float4*)&g[tid * 4];
  const float4 bv = *(const float4*)&b[tid * 4];
  ushort4 o;
  o.x = f2bf((xv.x - mu) * rs * gv.x + bv.x);
  o.y = f2bf((xv.y - mu) * rs * gv.y + bv.y);
  o.z = f2bf((xv.z - mu) * rs * gv.z + bv.z);
  o.w = f2bf((xv.w - mu) * rs * gv.w + bv.w);
  *(ushort4*)&out[(long)row * 1024 + tid * 4] = o;
}

// ---------------- bf16 GEMM: C[M,N] = A[M,K] * Bt[N,K]^T, templated epilogue ----------------
#define EPI_QKV 0
#define EPI_F32 1
#define EPI_RELU 2

template <int EPI>
__global__ __launch_bounds__(256, 3) void gemm_bt(
    const unsigned short* __restrict__ A, const unsigned short* __restrict__ Bt,
    int M, int N, int K,
    const float* __restrict__ bias, const float* __restrict__ resid,
    float* __restrict__ outF, unsigned short* __restrict__ outB,
    unsigned short* __restrict__ qb, unsigned short* __restrict__ kb,
    unsigned short* __restrict__ vTb) {
  // LDS holds 16B chunks; chunk (m, kc) stored at physical pc = kc ^ (m&7) -> conflict-free b128 reads
  __shared__ __attribute__((aligned(16))) unsigned short Alds[128 * 64];
  __shared__ __attribute__((aligned(16))) unsigned short Blds[128 * 64];
  const int tid = threadIdx.x;
  const int wave = tid >> 6, lane = tid & 63;
  const int quad = lane >> 4, l15 = lane & 15;
  const long tM = (long)blockIdx.x * 128;
  const long tN = (long)blockIdx.y * 128;
  const int wm = (wave >> 1) * 64, wn = (wave & 1) * 64;

  const unsigned short* aP[4];
  const unsigned short* bP[4];
  unsigned short* lA[4];
  unsigned short* lB[4];
#pragma unroll
  for (int qq = 0; qq < 4; qq++) {
    int p = (qq * 4 + wave) * 64 + lane;
    int m = p >> 3;
    int kc = (p & 7) ^ (m & 7);
    aP[qq] = A + (tM + m) * K + kc * 8;
    bP[qq] = Bt + (tN + m) * K + kc * 8;
    lA[qq] = Alds + (qq * 4 + wave) * 512;  // wave-uniform base, lane*16B appended by HW
    lB[qq] = Blds + (qq * 4 + wave) * 512;
  }

  f32x4 acc[4][4];
#pragma unroll
  for (int i = 0; i < 4; i++)
#pragma unroll
    for (int j = 0; j < 4; j++) acc[i][j] = (f32x4){0.f, 0.f, 0.f, 0.f};

  for (int k0 = 0; k0 < K; k0 += 64) {
    __syncthreads();
#pragma unroll
    for (int qq = 0; qq < 4; qq++) {
      load_lds16(aP[qq], lA[qq]);
      load_lds16(bP[qq], lB[qq]);
      aP[qq] += 64;
      bP[qq] += 64;
    }
    __syncthreads();
#pragma unroll
    for (int ks = 0; ks < 2; ks++) {
      bf16x8 af[4], bfr[4];
#pragma unroll
      for (int mt = 0; mt < 4; mt++) {
        int ml = wm + mt * 16 + l15;
        int pc = (ks * 4 + quad) ^ (ml & 7);
        af[mt] = *(const bf16x8*)&Alds[(ml * 8 + pc) * 8];
      }
#pragma unroll
      for (int nt = 0; nt < 4; nt++) {
        int nl = wn + nt * 16 + l15;
        int pc = (ks * 4 + quad) ^ (nl & 7);
        bfr[nt] = *(const bf16x8*)&Blds[(nl * 8 + pc) * 8];
      }
#pragma unroll
      for (int mt = 0; mt < 4; mt++)
#pragma unroll
        for (int nt = 0; nt < 4; nt++)
          acc[mt][nt] = __builtin_amdgcn_mfma_f32_16x16x32_bf16(af[mt], bfr[nt], acc[mt][nt], 0, 0, 0);
    }
  }

#pragma unroll
  for (int mt = 0; mt < 4; mt++) {
#pragma unroll
    for (int nt = 0; nt < 4; nt++) {
      const long col = tN + wn + nt * 16 + l15;
      const long row0 = tM + wm + mt * 16 + quad * 4;
      if (EPI == EPI_F32) {
        const float bv = bias[col];
#pragma unroll
        for (int r = 0; r < 4; r++) {
          long idx = (row0 + r) * N + col;
          outF[idx] = acc[mt][nt][r] + bv + resid[idx];
        }
      } else if (EPI == EPI_RELU) {
        const float bv = bias[col];
#pragma unroll
        for (int r = 0; r < 4; r++) {
          float v = acc[mt][nt][r] + bv;
          outB[(row0 + r) * N + col] = f2bf(v > 0.f ? v : 0.f);
        }
      } else {  // EPI_QKV: scatter into q[bh][t][d], k[bh][t][d], vT[bh][d][t]
        const int which = (int)(col >> 10);
        const int hh = (int)((col >> 6) & 15);
        const int dd = (int)(col & 63);
        const int b = (int)(row0 >> 10), t0 = (int)(row0 & 1023);
        if (which == 2) {
          // rows r=0..3 are consecutive t -> pack one ushort4 store
          ushort4 pk;
          pk.x = f2bf(acc[mt][nt][0]);
          pk.y = f2bf(acc[mt][nt][1]);
          pk.z = f2bf(acc[mt][nt][2]);
          pk.w = f2bf(acc[mt][nt][3]);
          *(ushort4*)&vTb[(long)(b * 16 + hh) * 65536 + dd * 1024 + t0] = pk;
        } else {
          unsigned short* dst = (which == 0 ? qb : kb);
#pragma unroll
          for (int r = 0; r < 4; r++)
            dst[((b * 16 + hh) * 1024 + t0 + r) * 64 + dd] = f2bf(acc[mt][nt][r]);
        }
      }
    }
  }
}

// ---------------- flash attention (no-max softmax): 128 q-rows per block ----------------
// Each wave owns two 16-row MFMA groups; K/V staged via swizzled global_load_lds.
__global__ __launch_bounds__(256, 4) void attn_kernel(const unsigned short* __restrict__ qb,
                                                      const unsigned short* __restrict__ kb,
                                                      const unsigned short* __restrict__ vTb,
                                                      unsigned short* __restrict__ out) {
  // K/V tiles as swizzled 16B chunks: chunk (row, kc) at phys pc = kc ^ (row&7)
  __shared__ __attribute__((aligned(16))) unsigned short Klds[64 * 64];      // [s][d]
  __shared__ __attribute__((aligned(16))) unsigned short Vlds[64 * 64];      // [d][s]
  __shared__ __attribute__((aligned(16))) unsigned short Plds[4 * 16 * 68];  // per-wave, stride 68
  const int bh = blockIdx.x;   // 0..127
  const int qt2 = blockIdx.y;  // 0..7
  const int tid = threadIdx.x;
  const int wave = tid >> 6, lane = tid & 63;
  const int quad = lane >> 4, l15 = lane & 15;

  const unsigned short* qp = qb + (long)bh * 65536;
  const unsigned short* kp = kb + (long)bh * 65536;
  const unsigned short* vp = vTb + (long)bh * 65536;

  bf16x8 qf[2][2];
#pragma unroll
  for (int g = 0; g < 2; g++) {
    const int qrow = qt2 * 128 + (wave * 2 + g) * 16 + l15;
    qf[g][0] = *(const bf16x8*)&qp[qrow * 64 + quad * 8];
    qf[g][1] = *(const bf16x8*)&qp[qrow * 64 + 32 + quad * 8];
  }

  f32x4 O[2][4];
  float l_r[2][4];
#pragma unroll
  for (int g = 0; g < 2; g++) {
#pragma unroll
    for (int nt = 0; nt < 4; nt++) O[g][nt] = (f32x4){0.f, 0.f, 0.f, 0.f};
#pragma unroll
    for (int r = 0; r < 4; r++) l_r[g][r] = 0.f;
  }

  unsigned short* Pl = Plds + wave * (16 * 68);
  const float cscale = 0.045084220f;  // (1/32) * log2(e)
  const int kmax = 2 * qt2 + 1;

  for (int kt = 0; kt <= kmax; kt++) {
    __syncthreads();
#pragma unroll
    for (int c = 0; c < 2; c++) {
      const int pb = (wave * 2 + c) * 64;
      const int p = pb + lane;
      const int m = p >> 3;
      const int kc = (p & 7) ^ (m & 7);
      load_lds16(kp + (kt * 64 + m) * 64 + kc * 8, Klds + pb * 8);
      load_lds16(vp + m * 1024 + kt * 64 + kc * 8, Vlds + pb * 8);
    }
    __syncthreads();

#pragma unroll
    for (int g = 0; g < 2; g++) {
      const int rowbase = qt2 * 128 + (wave * 2 + g) * 16;
      if (kt * 64 >= rowbase + 16) continue;  // entire group above-diagonal: all masked

      // S = Q K^T  (C-layout: col = s = nt*16+l15, row = quad*4+r)
      f32x4 S[4];
#pragma unroll
      for (int nt = 0; nt < 4; nt++) {
        const int row = nt * 16 + l15;
        const int pc0 = quad ^ (row & 7);
        const int pc1 = (quad + 4) ^ (row & 7);
        bf16x8 kf0 = *(const bf16x8*)&Klds[(row * 8 + pc0) * 8];
        bf16x8 kf1 = *(const bf16x8*)&Klds[(row * 8 + pc1) * 8];
        f32x4 s = (f32x4){0.f, 0.f, 0.f, 0.f};
        s = __builtin_amdgcn_mfma_f32_16x16x32_bf16(qf[g][0], kf0, s, 0, 0, 0);
        s = __builtin_amdgcn_mfma_f32_16x16x32_bf16(qf[g][1], kf1, s, 0, 0, 0);
        S[nt] = s;
      }

      const bool diag = (kt * 64 + 63 > rowbase);
      const int tb = rowbase + quad * 4;
#pragma unroll
      for (int nt = 0; nt < 4; nt++) {
        const int sg = kt * 64 + nt * 16 + l15;
#pragma unroll
        for (int r = 0; r < 4; r++) {
          float pv = exp2f(S[nt][r] * cscale);
          if (diag && sg > tb + r) pv = 0.f;
          l_r[g][r] += pv;
          Pl[(quad * 4 + r) * 68 + nt * 16 + l15] = f2bf(pv);
        }
      }
      __threadfence_block();  // drain ds_writes before cross-lane ds_reads

#pragma unroll
      for (int ks2 = 0; ks2 < 2; ks2++) {
        bf16x8 pa = *(const bf16x8*)&Pl[l15 * 68 + ks2 * 32 + quad * 8];
#pragma unroll
        for (int nt = 0; nt < 4; nt++) {
          const int d = nt * 16 + l15;
          const int pc = (ks2 * 4 + quad) ^ (d & 7);
          bf16x8 vf = *(const bf16x8*)&Vlds[(d * 8 + pc) * 8];
          O[g][nt] = __builtin_amdgcn_mfma_f32_16x16x32_bf16(pa, vf, O[g][nt], 0, 0, 0);
        }
      }
      __threadfence_block();  // P region reused by next group/iter
    }
  }

  const int b = bh >> 4, h = bh & 15;
#pragma unroll
  for (int g = 0; g < 2; g++) {
#pragma unroll
    for (int r = 0; r < 4; r++) {
      float lv = l_r[g][r];
      lv += __shfl_xor(lv, 1);
      lv += __shfl_xor(lv, 2);
      lv += __shfl_xor(lv, 4);
      lv += __shfl_xor(lv, 8);
      lv = __builtin_amdgcn_rcpf(lv);
      const int t = qt2 * 128 + (wave * 2 + g) * 16 + quad * 4 + r;
#pragma unroll
      for (int nt = 0; nt < 4; nt++)
        out[(long)(b * 1024 + t) * 1024 + h * 64 + nt * 16 + l15] = f2bf(O[g][nt][r] * lv);
    }
  }
}

extern "C" void kernel_launch(void* const* d_in, const int* in_sizes, int n_in,
                              void* d_out, int out_size, void* d_ws, size_t ws_size,
                              hipStream_t stream) {
  const float* x = (const float*)d_in[0];
  const float* wq = (const float*)d_in[1];
  const float* wk = (const float*)d_in[2];
  const float* wv = (const float*)d_in[3];
  const float* w_proj = (const float*)d_in[4];
  const float* b_proj = (const float*)d_in[5];
  const float* ln1_g = (const float*)d_in[6];
  const float* ln1_b = (const float*)d_in[7];
  const float* ln2_g = (const float*)d_in[8];
  const float* ln2_b = (const float*)d_in[9];
  const float* w1 = (const float*)d_in[10];
  const float* b1 = (const float*)d_in[11];
  const float* w2 = (const float*)d_in[12];
  const float* b2 = (const float*)d_in[13];
  float* out = (float*)d_out;

  char* w = (char*)d_ws;
  unsigned short* h1 = (unsigned short*)w;      w += (size_t)8192 * 1024 * 2;   // 16MB (reused as attnO)
  unsigned short* wqkvt = (unsigned short*)w;   w += (size_t)3072 * 1024 * 2;   // 6MB
  unsigned short* wprojt = (unsigned short*)w;  w += (size_t)1024 * 1024 * 2;   // 2MB
  unsigned short* w1t = (unsigned short*)w;     w += (size_t)4096 * 1024 * 2;   // 8MB
  unsigned short* w2t = (unsigned short*)w;     w += (size_t)4096 * 1024 * 2;   // 8MB
  unsigned short* qbuf = (unsigned short*)w;    w += (size_t)128 * 1024 * 64 * 2;  // 16MB (reused as h2)
  unsigned short* kbuf = (unsigned short*)w;    w += (size_t)128 * 1024 * 64 * 2;  // 16MB
  unsigned short* vTbuf = (unsigned short*)w;   w += (size_t)128 * 1024 * 64 * 2;  // 16MB
  unsigned short* act = (unsigned short*)w;     w += (size_t)8192 * 4096 * 2;      // 64MB
  unsigned short* attnO = h1;  // h1 dead after QKV gemm
  unsigned short* h2 = qbuf;   // qbuf dead after attention

  transpose_all<<<12288, 256, 0, stream>>>(wq, wk, wv, w_proj, w1, w2,
                                           wqkvt, wprojt, w1t, w2t);

  ln_kernel<<<8192, 256, 0, stream>>>(x, ln1_g, ln1_b, h1);

  gemm_bt<EPI_QKV><<<dim3(64, 24), 256, 0, stream>>>(h1, wqkvt, 8192, 3072, 1024,
                                                     nullptr, nullptr, nullptr, nullptr,
                                                     qbuf, kbuf, vTbuf);

  attn_kernel<<<dim3(128, 8), 256, 0, stream>>>(qbuf, kbuf, vTbuf, attnO);

  gemm_bt<EPI_F32><<<dim3(64, 8), 256, 0, stream>>>(attnO, wprojt, 8192, 1024, 1024,
                                                    b_proj, x, out, nullptr,
                                                    nullptr, nullptr, nullptr);

  ln_kernel<<<8192, 256, 0, stream>>>(out, ln2_g, ln2_b, h2);

  gemm_bt<EPI_RELU><<<dim3(64, 32), 256, 0, stream>>>(h2, w1t, 8192, 4096, 1024,
                                                      b1, nullptr, nullptr, act,
                                                      nullptr, nullptr, nullptr);

  gemm_bt<EPI_F32><<<dim3(64, 8), 256, 0, stream>>>(act, w2t, 8192, 1024, 4096,
                                                    b2, out, out, nullptr,
                                                    nullptr, nullptr, nullptr);
}

// Round 5
// 438.399 us; speedup vs baseline: 1.1890x; 1.0262x over previous
//
#include <hip/hip_runtime.h>
#include <cstdint>

typedef __attribute__((ext_vector_type(8))) __bf16 bf16x8;
typedef __attribute__((ext_vector_type(4))) float f32x4;

__device__ __forceinline__ unsigned short f2bf(float f) {
  union { float f; unsigned int u; } v; v.f = f;
  unsigned int u = v.u;
  return (unsigned short)((u + 0x7FFFu + ((u >> 16) & 1u)) >> 16);
}

__device__ __forceinline__ void load_lds16(const unsigned short* g, unsigned short* l) {
  __builtin_amdgcn_global_load_lds(
      (const __attribute__((address_space(1))) unsigned int*)g,
      (__attribute__((address_space(3))) unsigned int*)l, 16, 0, 0);
}

// ---------------- fused prep: weight transposes (fp32 [K][N] -> bf16 [N][K]) + LN1 ----------------
__global__ void prep_kernel(const float* __restrict__ wq, const float* __restrict__ wk,
                            const float* __restrict__ wv, const float* __restrict__ w_proj,
                            const float* __restrict__ w1, const float* __restrict__ w2,
                            const float* __restrict__ x, const float* __restrict__ ln1_g,
                            const float* __restrict__ ln1_b,
                            unsigned short* __restrict__ qkvt, unsigned short* __restrict__ projt,
                            unsigned short* __restrict__ w1t, unsigned short* __restrict__ w2t,
                            unsigned short* __restrict__ h1) {
  __shared__ float tile[32][33];
  __shared__ float a1[4], a2[4];
  const int id = blockIdx.x;
  const int tid = threadIdx.x;

  if (id >= 12288) {  // ---- LN1 row ----
    const int row = id - 12288;
    const int wave = tid >> 6, lane = tid & 63;
    const float4 xv = *(const float4*)&x[(long)row * 1024 + tid * 4];
    float s1 = xv.x + xv.y + xv.z + xv.w;
    float s2 = xv.x * xv.x + xv.y * xv.y + xv.z * xv.z + xv.w * xv.w;
#pragma unroll
    for (int m = 1; m < 64; m <<= 1) { s1 += __shfl_xor(s1, m); s2 += __shfl_xor(s2, m); }
    if (lane == 0) { a1[wave] = s1; a2[wave] = s2; }
    __syncthreads();
    s1 = a1[0] + a1[1] + a1[2] + a1[3];
    s2 = a2[0] + a2[1] + a2[2] + a2[3];
    const float mu = s1 * (1.f / 1024.f);
    const float var = s2 * (1.f / 1024.f) - mu * mu;
    const float rs = rsqrtf(var + 1e-5f);
    const float4 gv = *(const float4*)&ln1_g[tid * 4];
    const float4 bv = *(const float4*)&ln1_b[tid * 4];
    ushort4 o;
    o.x = f2bf((xv.x - mu) * rs * gv.x + bv.x);
    o.y = f2bf((xv.y - mu) * rs * gv.y + bv.y);
    o.z = f2bf((xv.z - mu) * rs * gv.z + bv.z);
    o.w = f2bf((xv.w - mu) * rs * gv.w + bv.w);
    *(ushort4*)&h1[(long)row * 1024 + tid * 4] = o;
    return;
  }

  // ---- weight transpose tile ----
  const float* src;
  unsigned short* dst;
  int K, N, nt, kt;
  if (id < 3072) {  // qkv: which(3) x slice(16) x ntile(2) x ktile(32)
    const int which = id >> 10, rem = id & 1023;
    const int slice = rem >> 6, t = rem & 63;
    src = (which == 0 ? wq : which == 1 ? wk : wv) + (long)slice * 65536;
    dst = qkvt + (long)which * 1048576 + (long)slice * 65536;
    K = 1024; N = 64;
    nt = (t & 1) * 32; kt = (t >> 1) * 32;
  } else if (id < 4096) {  // proj
    const int t = id - 3072;
    src = w_proj; dst = projt; K = 1024; N = 1024;
    nt = (t & 31) * 32; kt = (t >> 5) * 32;
  } else if (id < 8192) {  // w1
    const int t = id - 4096;
    src = w1; dst = w1t; K = 1024; N = 4096;
    nt = (t & 127) * 32; kt = (t >> 7) * 32;
  } else {  // w2
    const int t = id - 8192;
    src = w2; dst = w2t; K = 4096; N = 1024;
    nt = (t & 31) * 32; kt = (t >> 5) * 32;
  }
  const int tx = tid & 31, ty = tid >> 5;
#pragma unroll
  for (int i = 0; i < 4; i++)
    tile[ty + 8 * i][tx] = src[(long)(kt + ty + 8 * i) * N + nt + tx];
  __syncthreads();
#pragma unroll
  for (int i = 0; i < 4; i++)
    dst[(long)(nt + ty + 8 * i) * K + kt + tx] = f2bf(tile[tx][ty + 8 * i]);
}

// ---------------- LayerNorm fp32 -> bf16 (one row of 1024 per block) ----------------
__global__ __launch_bounds__(256, 4) void ln_kernel(const float* __restrict__ x,
                                                    const float* __restrict__ g,
                                                    const float* __restrict__ b,
                                                    unsigned short* __restrict__ out) {
  const int row = blockIdx.x, tid = threadIdx.x;
  const int wave = tid >> 6, lane = tid & 63;
  const float4 xv = *(const float4*)&x[(long)row * 1024 + tid * 4];
  float s1 = xv.x + xv.y + xv.z + xv.w;
  float s2 = xv.x * xv.x + xv.y * xv.y + xv.z * xv.z + xv.w * xv.w;
#pragma unroll
  for (int m = 1; m < 64; m <<= 1) { s1 += __shfl_xor(s1, m); s2 += __shfl_xor(s2, m); }
  __shared__ float a1[4], a2[4];
  if (lane == 0) { a1[wave] = s1; a2[wave] = s2; }
  __syncthreads();
  s1 = a1[0] + a1[1] + a1[2] + a1[3];
  s2 = a2[0] + a2[1] + a2[2] + a2[3];
  const float mu = s1 * (1.f / 1024.f);
  const float var = s2 * (1.f / 1024.f) - mu * mu;
  const float rs = rsqrtf(var + 1e-5f);
  const float4 gv = *(const float4*)&g[tid * 4];
  const float4 bv = *(const float4*)&b[tid * 4];
  ushort4 o;
  o.x = f2bf((xv.x - mu) * rs * gv.x + bv.x);
  o.y = f2bf((xv.y - mu) * rs * gv.y + bv.y);
  o.z = f2bf((xv.z - mu) * rs * gv.z + bv.z);
  o.w = f2bf((xv.w - mu) * rs * gv.w + bv.w);
  *(ushort4*)&out[(long)row * 1024 + tid * 4] = o;
}

// ---------------- bf16 GEMM: C[M,N] = A[M,K] * Bt[N,K]^T, templated epilogue ----------------
#define EPI_QKV 0
#define EPI_F32 1
#define EPI_RELU 2

template <int EPI>
__global__ __launch_bounds__(256, 3) void gemm_bt(
    const unsigned short* __restrict__ A, const unsigned short* __restrict__ Bt,
    int M, int N, int K,
    const float* __restrict__ bias, const float* __restrict__ resid,
    float* __restrict__ outF, unsigned short* __restrict__ outB,
    unsigned short* __restrict__ qb, unsigned short* __restrict__ kb,
    unsigned short* __restrict__ vTb) {
  // LDS holds 16B chunks; chunk (m, kc) stored at physical pc = kc ^ (m&7) -> conflict-free b128 reads
  __shared__ __attribute__((aligned(16))) unsigned short Alds[128 * 64];
  __shared__ __attribute__((aligned(16))) unsigned short Blds[128 * 64];
  const int tid = threadIdx.x;
  const int wave = tid >> 6, lane = tid & 63;
  const int quad = lane >> 4, l15 = lane & 15;
  const long tM = (long)blockIdx.x * 128;
  const long tN = (long)blockIdx.y * 128;
  const int wm = (wave >> 1) * 64, wn = (wave & 1) * 64;

  const unsigned short* aP[4];
  const unsigned short* bP[4];
  unsigned short* lA[4];
  unsigned short* lB[4];
#pragma unroll
  for (int qq = 0; qq < 4; qq++) {
    int p = (qq * 4 + wave) * 64 + lane;
    int m = p >> 3;
    int kc = (p & 7) ^ (m & 7);
    aP[qq] = A + (tM + m) * K + kc * 8;
    bP[qq] = Bt + (tN + m) * K + kc * 8;
    lA[qq] = Alds + (qq * 4 + wave) * 512;  // wave-uniform base, lane*16B appended by HW
    lB[qq] = Blds + (qq * 4 + wave) * 512;
  }

  f32x4 acc[4][4];
#pragma unroll
  for (int i = 0; i < 4; i++)
#pragma unroll
    for (int j = 0; j < 4; j++) acc[i][j] = (f32x4){0.f, 0.f, 0.f, 0.f};

  for (int k0 = 0; k0 < K; k0 += 64) {
    __syncthreads();
#pragma unroll
    for (int qq = 0; qq < 4; qq++) {
      load_lds16(aP[qq], lA[qq]);
      load_lds16(bP[qq], lB[qq]);
      aP[qq] += 64;
      bP[qq] += 64;
    }
    __syncthreads();
#pragma unroll
    for (int ks = 0; ks < 2; ks++) {
      bf16x8 af[4], bfr[4];
#pragma unroll
      for (int mt = 0; mt < 4; mt++) {
        int ml = wm + mt * 16 + l15;
        int pc = (ks * 4 + quad) ^ (ml & 7);
        af[mt] = *(const bf16x8*)&Alds[(ml * 8 + pc) * 8];
      }
#pragma unroll
      for (int nt = 0; nt < 4; nt++) {
        int nl = wn + nt * 16 + l15;
        int pc = (ks * 4 + quad) ^ (nl & 7);
        bfr[nt] = *(const bf16x8*)&Blds[(nl * 8 + pc) * 8];
      }
#pragma unroll
      for (int mt = 0; mt < 4; mt++)
#pragma unroll
        for (int nt = 0; nt < 4; nt++)
          acc[mt][nt] = __builtin_amdgcn_mfma_f32_16x16x32_bf16(af[mt], bfr[nt], acc[mt][nt], 0, 0, 0);
    }
  }

#pragma unroll
  for (int mt = 0; mt < 4; mt++) {
#pragma unroll
    for (int nt = 0; nt < 4; nt++) {
      const long col = tN + wn + nt * 16 + l15;
      const long row0 = tM + wm + mt * 16 + quad * 4;
      if (EPI == EPI_F32) {
        const float bv = bias[col];
#pragma unroll
        for (int r = 0; r < 4; r++) {
          long idx = (row0 + r) * N + col;
          outF[idx] = acc[mt][nt][r] + bv + resid[idx];
        }
      } else if (EPI == EPI_RELU) {
        const float bv = bias[col];
#pragma unroll
        for (int r = 0; r < 4; r++) {
          float v = acc[mt][nt][r] + bv;
          outB[(row0 + r) * N + col] = f2bf(v > 0.f ? v : 0.f);
        }
      } else {  // EPI_QKV: scatter into q[bh][t][d], k[bh][t][d], vT[bh][d][t]
        const int which = (int)(col >> 10);
        const int hh = (int)((col >> 6) & 15);
        const int dd = (int)(col & 63);
        const int b = (int)(row0 >> 10), t0 = (int)(row0 & 1023);
        if (which == 2) {
          ushort4 pk;
          pk.x = f2bf(acc[mt][nt][0]);
          pk.y = f2bf(acc[mt][nt][1]);
          pk.z = f2bf(acc[mt][nt][2]);
          pk.w = f2bf(acc[mt][nt][3]);
          *(ushort4*)&vTb[(long)(b * 16 + hh) * 65536 + dd * 1024 + t0] = pk;
        } else {
          unsigned short* dst = (which == 0 ? qb : kb);
#pragma unroll
          for (int r = 0; r < 4; r++)
            dst[((b * 16 + hh) * 1024 + t0 + r) * 64 + dd] = f2bf(acc[mt][nt][r]);
        }
      }
    }
  }
}

// ---------------- flash attention (no-max softmax), balanced q-tile pairing ----------------
// Block (bh, j) handles q-tiles qt2 = j and 7-j (128 rows each) sequentially:
// uniform 18 kt-tiles / 9 staging rounds per block regardless of j. Two K/V tiles
// staged per barrier via swizzled global_load_lds.
__global__ __launch_bounds__(256, 2) void attn_kernel(const unsigned short* __restrict__ qb,
                                                      const unsigned short* __restrict__ kb,
                                                      const unsigned short* __restrict__ vTb,
                                                      unsigned short* __restrict__ out) {
  // chunk (row, kc) of each 64x64 tile at phys pc = kc ^ (row&7)
  __shared__ __attribute__((aligned(16))) unsigned short Klds[2][64 * 64];   // [s][d]
  __shared__ __attribute__((aligned(16))) unsigned short Vlds[2][64 * 64];   // [d][s]
  __shared__ __attribute__((aligned(16))) unsigned short Plds[4 * 16 * 68];  // per-wave, stride 68
  const int bh = blockIdx.x;  // 0..127
  const int j = blockIdx.y;   // 0..3
  const int tid = threadIdx.x;
  const int wave = tid >> 6, lane = tid & 63;
  const int quad = lane >> 4, l15 = lane & 15;

  const unsigned short* qp = qb + (long)bh * 65536;
  const unsigned short* kp = kb + (long)bh * 65536;
  const unsigned short* vp = vTb + (long)bh * 65536;
  const int b = bh >> 4, h = bh & 15;

  unsigned short* Pl = Plds + wave * (16 * 68);
  const float cscale = 0.045084220f;  // (1/32) * log2(e)

  for (int ph = 0; ph < 2; ph++) {
    const int qt2 = ph ? 7 - j : j;

    bf16x8 qf[2][2];
#pragma unroll
    for (int g = 0; g < 2; g++) {
      const int qrow = qt2 * 128 + (wave * 2 + g) * 16 + l15;
      qf[g][0] = *(const bf16x8*)&qp[qrow * 64 + quad * 8];
      qf[g][1] = *(const bf16x8*)&qp[qrow * 64 + 32 + quad * 8];
    }

    f32x4 O[2][4];
    float l_r[2][4];
#pragma unroll
    for (int g = 0; g < 2; g++) {
#pragma unroll
      for (int nt = 0; nt < 4; nt++) O[g][nt] = (f32x4){0.f, 0.f, 0.f, 0.f};
#pragma unroll
      for (int r = 0; r < 4; r++) l_r[g][r] = 0.f;
    }

    const int nstage = qt2 + 1;  // kt tiles = 2*qt2+2, staged 2 per round
    for (int st = 0; st < nstage; st++) {
      __syncthreads();
#pragma unroll
      for (int c = 0; c < 4; c++) {
        const int pb = c * 256 + wave * 64;  // wave-uniform chunk base (0..1023)
        const int p = pb + lane;
        const int sub = p >> 9;              // uniform within wave (pb % 64 == 0)
        const int q_ = p & 511;
        const int m = q_ >> 3;
        const int kc = (q_ & 7) ^ (m & 7);
        const int kt = st * 2 + sub;
        load_lds16(kp + (kt * 64 + m) * 64 + kc * 8, (unsigned short*)Klds + pb * 8);
        load_lds16(vp + m * 1024 + kt * 64 + kc * 8, (unsigned short*)Vlds + pb * 8);
      }
      __syncthreads();

#pragma unroll
      for (int sub = 0; sub < 2; sub++) {
        const int kt = st * 2 + sub;
        const unsigned short* Ksub = (const unsigned short*)Klds + sub * 4096;
        const unsigned short* Vsub = (const unsigned short*)Vlds + sub * 4096;

#pragma unroll
        for (int g = 0; g < 2; g++) {
          const int rowbase = qt2 * 128 + (wave * 2 + g) * 16;
          if (kt * 64 >= rowbase + 16) continue;  // fully masked group

          // S = Q K^T  (C-layout: col = s = nt*16+l15, row = quad*4+r)
          f32x4 S[4];
#pragma unroll
          for (int nt = 0; nt < 4; nt++) {
            const int row = nt * 16 + l15;
            const int pc0 = quad ^ (row & 7);
            const int pc1 = (quad + 4) ^ (row & 7);
            bf16x8 kf0 = *(const bf16x8*)&Ksub[(row * 8 + pc0) * 8];
            bf16x8 kf1 = *(const bf16x8*)&Ksub[(row * 8 + pc1) * 8];
            f32x4 s = (f32x4){0.f, 0.f, 0.f, 0.f};
            s = __builtin_amdgcn_mfma_f32_16x16x32_bf16(qf[g][0], kf0, s, 0, 0, 0);
            s = __builtin_amdgcn_mfma_f32_16x16x32_bf16(qf[g][1], kf1, s, 0, 0, 0);
            S[nt] = s;
          }

          const bool diag = (kt * 64 + 63 > rowbase);
          const int tb = rowbase + quad * 4;
#pragma unroll
          for (int nt = 0; nt < 4; nt++) {
            const int sg = kt * 64 + nt * 16 + l15;
#pragma unroll
            for (int r = 0; r < 4; r++) {
              float pv = exp2f(S[nt][r] * cscale);
              if (diag && sg > tb + r) pv = 0.f;
              l_r[g][r] += pv;
              Pl[(quad * 4 + r) * 68 + nt * 16 + l15] = f2bf(pv);
            }
          }
          __threadfence_block();  // drain ds_writes before cross-lane ds_reads

#pragma unroll
          for (int ks2 = 0; ks2 < 2; ks2++) {
            bf16x8 pa = *(const bf16x8*)&Pl[l15 * 68 + ks2 * 32 + quad * 8];
#pragma unroll
            for (int nt = 0; nt < 4; nt++) {
              const int d = nt * 16 + l15;
              const int pc = (ks2 * 4 + quad) ^ (d & 7);
              bf16x8 vf = *(const bf16x8*)&Vsub[(d * 8 + pc) * 8];
              O[g][nt] = __builtin_amdgcn_mfma_f32_16x16x32_bf16(pa, vf, O[g][nt], 0, 0, 0);
            }
          }
          __threadfence_block();  // P region reused by next group/sub
        }
      }
    }

#pragma unroll
    for (int g = 0; g < 2; g++) {
#pragma unroll
      for (int r = 0; r < 4; r++) {
        float lv = l_r[g][r];
        lv += __shfl_xor(lv, 1);
        lv += __shfl_xor(lv, 2);
        lv += __shfl_xor(lv, 4);
        lv += __shfl_xor(lv, 8);
        lv = __builtin_amdgcn_rcpf(lv);
        const int t = qt2 * 128 + (wave * 2 + g) * 16 + quad * 4 + r;
#pragma unroll
        for (int nt = 0; nt < 4; nt++)
          out[(long)(b * 1024 + t) * 1024 + h * 64 + nt * 16 + l15] = f2bf(O[g][nt][r] * lv);
      }
    }
  }
}

extern "C" void kernel_launch(void* const* d_in, const int* in_sizes, int n_in,
                              void* d_out, int out_size, void* d_ws, size_t ws_size,
                              hipStream_t stream) {
  const float* x = (const float*)d_in[0];
  const float* wq = (const float*)d_in[1];
  const float* wk = (const float*)d_in[2];
  const float* wv = (const float*)d_in[3];
  const float* w_proj = (const float*)d_in[4];
  const float* b_proj = (const float*)d_in[5];
  const float* ln1_g = (const float*)d_in[6];
  const float* ln1_b = (const float*)d_in[7];
  const float* ln2_g = (const float*)d_in[8];
  const float* ln2_b = (const float*)d_in[9];
  const float* w1 = (const float*)d_in[10];
  const float* b1 = (const float*)d_in[11];
  const float* w2 = (const float*)d_in[12];
  const float* b2 = (const float*)d_in[13];
  float* out = (float*)d_out;

  char* w = (char*)d_ws;
  unsigned short* h1 = (unsigned short*)w;      w += (size_t)8192 * 1024 * 2;   // 16MB (reused as attnO)
  unsigned short* wqkvt = (unsigned short*)w;   w += (size_t)3072 * 1024 * 2;   // 6MB
  unsigned short* wprojt = (unsigned short*)w;  w += (size_t)1024 * 1024 * 2;   // 2MB
  unsigned short* w1t = (unsigned short*)w;     w += (size_t)4096 * 1024 * 2;   // 8MB
  unsigned short* w2t = (unsigned short*)w;     w += (size_t)4096 * 1024 * 2;   // 8MB
  unsigned short* qbuf = (unsigned short*)w;    w += (size_t)128 * 1024 * 64 * 2;  // 16MB (reused as h2)
  unsigned short* kbuf = (unsigned short*)w;    w += (size_t)128 * 1024 * 64 * 2;  // 16MB
  unsigned short* vTbuf = (unsigned short*)w;   w += (size_t)128 * 1024 * 64 * 2;  // 16MB
  unsigned short* act = (unsigned short*)w;     w += (size_t)8192 * 4096 * 2;      // 64MB
  unsigned short* attnO = h1;  // h1 dead after QKV gemm
  unsigned short* h2 = qbuf;   // qbuf dead after attention

  prep_kernel<<<12288 + 8192, 256, 0, stream>>>(wq, wk, wv, w_proj, w1, w2,
                                                x, ln1_g, ln1_b,
                                                wqkvt, wprojt, w1t, w2t, h1);

  gemm_bt<EPI_QKV><<<dim3(64, 24), 256, 0, stream>>>(h1, wqkvt, 8192, 3072, 1024,
                                                     nullptr, nullptr, nullptr, nullptr,
                                                     qbuf, kbuf, vTbuf);

  attn_kernel<<<dim3(128, 4), 256, 0, stream>>>(qbuf, kbuf, vTbuf, attnO);

  gemm_bt<EPI_F32><<<dim3(64, 8), 256, 0, stream>>>(attnO, wprojt, 8192, 1024, 1024,
                                                    b_proj, x, out, nullptr,
                                                    nullptr, nullptr, nullptr);

  ln_kernel<<<8192, 256, 0, stream>>>(out, ln2_g, ln2_b, h2);

  gemm_bt<EPI_RELU><<<dim3(64, 32), 256, 0, stream>>>(h2, w1t, 8192, 4096, 1024,
                                                      b1, nullptr, nullptr, act,
                                                      nullptr, nullptr, nullptr);

  gemm_bt<EPI_F32><<<dim3(64, 8), 256, 0, stream>>>(act, w2t, 8192, 1024, 4096,
                                                    b2, out, out, nullptr,
                                                    nullptr, nullptr, nullptr);
}